// Round 13
// baseline (147.366 us; speedup 1.0000x reference)
//
#include <hip/hip_runtime.h>

#define DIM 64
#define NCODE 1024

typedef __attribute__((ext_vector_type(8))) short bf16x8;
typedef __attribute__((ext_vector_type(4))) float f32x4;

// ---- small ws (8.3 KB) ----
#define WSO_HIST  0        // float[1024]
#define WSO_LOSS  4096     // float
#define WSO_COUNT 4100     // int
#define WSO_MAX4  4112     // float[4]
#define WSO_CBN   4160     // float[1024]

// ---- big scratch in d_out's out_xq region (dead before epilogue writes it) ----
// cbt (FRAGMENT-MAJOR bf16 hi/lo codebook) @0 (262144 B) | list @262144 (131072 B)
// cbt layout: chunk c (64 codes), wave-tile w (16 codes): segment at (c*4+w)*4096,
//   4 pieces of 1024B: [bh0|bh1|bl0|bl1]; lane l's 16B at l*16 within a piece.
//   piece content for lane l (g=l>>4, col=l&15): code c*64+w*16+col,
//   bh0 = hi dims [g*8, g*8+8) ; bh1 = hi dims [32+g*8, ...) ; bl0/bl1 = lo same.

__device__ __forceinline__ unsigned short f2bf(float f) {
    unsigned u = __float_as_uint(f);
    unsigned r = (u + 0x7FFFu + ((u >> 16) & 1u)) >> 16;   // RNE
    return (unsigned short)r;
}

__device__ __forceinline__ void gload16(const void* g, void* l) {
    __builtin_amdgcn_global_load_lds(
        (const __attribute__((address_space(1))) unsigned int*)g,
        (__attribute__((address_space(3))) unsigned int*)l, 16, 0, 0);
}

// ---- kernel 0: prep (4 x 256): cbn, fragment-major bf16 codebook, zeros ----
__global__ __launch_bounds__(256) void vq_prep(const float* __restrict__ cb,
                                               char* __restrict__ ws,
                                               char* __restrict__ cbt) {
    __shared__ float red[256];
    const int t = threadIdx.x;
    const int k = blockIdx.x * 256 + t;

    float cv[64];
#pragma unroll
    for (int d = 0; d < DIM; ++d) cv[d] = cb[d * NCODE + k];

    float s = 0.f;
#pragma unroll
    for (int d = 0; d < DIM; ++d) s = fmaf(cv[d], cv[d], s);

    ((float*)(ws + WSO_CBN))[k] = s;
    ((float*)(ws + WSO_HIST))[k] = 0.f;

    unsigned short hi[64], lo[64];
#pragma unroll
    for (int d = 0; d < DIM; ++d) {
        unsigned short h = f2bf(cv[d]);
        float hf = __uint_as_float(((unsigned)h) << 16);
        hi[d] = h;
        lo[d] = f2bf(cv[d] - hf);
    }

    // fragment-major scatter (coalesces across consecutive k within a 16-code tile)
    const int c = k >> 6, cc = k & 63, wv = cc >> 4, col = cc & 15;
    char* base = cbt + (size_t)(c * 4 + wv) * 4096;
#pragma unroll
    for (int g = 0; g < 4; ++g) {
        bf16x8 h0v, h1v, l0v, l1v;
#pragma unroll
        for (int e = 0; e < 8; ++e) {
            h0v[e] = (short)hi[g * 8 + e];
            h1v[e] = (short)hi[32 + g * 8 + e];
            l0v[e] = (short)lo[g * 8 + e];
            l1v[e] = (short)lo[32 + g * 8 + e];
        }
        const int off = (g * 16 + col) * 16;
        *(bf16x8*)(base + off)        = h0v;
        *(bf16x8*)(base + 1024 + off) = h1v;
        *(bf16x8*)(base + 2048 + off) = l0v;
        *(bf16x8*)(base + 3072 + off) = l1v;
    }

    red[t] = s;
    __syncthreads();
    for (int m = 128; m > 0; m >>= 1) {
        if (t < m) red[t] = fmaxf(red[t], red[t + m]);
        __syncthreads();
    }
    if (t == 0) {
        ((float*)(ws + WSO_MAX4))[blockIdx.x] = red[0];
        if (blockIdx.x == 0) {
            *(float*)(ws + WSO_LOSS) = 0.f;
            *(int*)(ws + WSO_COUNT) = 0;
        }
    }
}

// ---- kernel 1: double-bf16 MFMA distances, BARRIER-FREE hot loop ----
// B-fragments read DIRECTLY from L2-resident fragment-major cbt (coalesced 1KB/wave),
// manually double-buffered in registers. No LDS for codebook -> no per-chunk
// vmcnt(0)+barrier drain (the stall that capped R5-R12 at ~70us). LDS 20.7 KB.
// Distance math bit-identical to R5/R12 (same MFMA operand values & order).
__global__ __launch_bounds__(256, 2) void vq_mfma(const float* __restrict__ x,
                                                  const char* __restrict__ cbt,
                                                  char* __restrict__ ws,
                                                  unsigned short* __restrict__ list,
                                                  float* __restrict__ out_idx) {
    // LDS: bX 16384 | cbn_s 4096 | xx_s 256 ; reduce scratch overlays bX post-loop
    __shared__ __align__(16) char sm[20736];
    char*  bX    = sm;
    float* cbn_s = (float*)(sm + 16384);
    float* xx_s  = (float*)(sm + 20480);
    float* R1    = (float*)sm;            // overlay (after post-loop barrier)
    float* R2v   = R1 + 256;
    int*   RIv   = (int*)(R2v + 256);

    const int t = threadIdx.x, w = t >> 6, lane = t & 63;
    const int r0 = blockIdx.x * 64;

    const float* mb4 = (const float*)(ws + WSO_MAX4);
    const float maxcbn = fmaxf(fmaxf(mb4[0], mb4[1]), fmaxf(mb4[2], mb4[3]));

    // cbn async load (drained at the one staging barrier)
    gload16((const char*)(ws + WSO_CBN) + ((size_t)w * 64 + lane) * 16, (char*)cbn_s + w * 1024);

    // --- stage bX (hi/lo bf16, XOR-swizzled) + xx ---
    {
        const int row = t >> 2, q = t & 3;
        const float4* xp = (const float4*)(x + (size_t)(r0 + row) * DIM + q * 16);
        float4 v0 = xp[0], v1 = xp[1], v2 = xp[2], v3 = xp[3];
        float p = 0.f;
        p = fmaf(v0.x, v0.x, p); p = fmaf(v0.y, v0.y, p); p = fmaf(v0.z, v0.z, p); p = fmaf(v0.w, v0.w, p);
        p = fmaf(v1.x, v1.x, p); p = fmaf(v1.y, v1.y, p); p = fmaf(v1.z, v1.z, p); p = fmaf(v1.w, v1.w, p);
        p = fmaf(v2.x, v2.x, p); p = fmaf(v2.y, v2.y, p); p = fmaf(v2.z, v2.z, p); p = fmaf(v2.w, v2.w, p);
        p = fmaf(v3.x, v3.x, p); p = fmaf(v3.y, v3.y, p); p = fmaf(v3.z, v3.z, p); p = fmaf(v3.w, v3.w, p);
        p += __shfl_xor(p, 1);
        p += __shfl_xor(p, 2);
        if (q == 0) xx_s[row] = p;

        float hv[16] = {v0.x, v0.y, v0.z, v0.w, v1.x, v1.y, v1.z, v1.w,
                        v2.x, v2.y, v2.z, v2.w, v3.x, v3.y, v3.z, v3.w};
        bf16x8 ph[2], pl[2];
#pragma unroll
        for (int h = 0; h < 2; ++h)
#pragma unroll
            for (int e = 0; e < 8; ++e) {
                float v = hv[h * 8 + e];
                unsigned short hb = f2bf(v);
                float hf = __uint_as_float(((unsigned)hb) << 16);
                ph[h][e] = (short)hb;
                pl[h][e] = (short)f2bf(v - hf);
            }
        const int sw = row & 7;
        char* base = bX + row * 256;
#pragma unroll
        for (int h = 0; h < 2; ++h) {
            int s3 = (2 * q + h) ^ sw;
            *(bf16x8*)(base + (s3 & 7) * 16)        = ph[h];
            *(bf16x8*)(base + (8 | (s3 & 7)) * 16)  = pl[h];
        }
    }
    __syncthreads();   // bX + cbn ready (the ONLY staging barrier)

    // --- A fragments (hi/lo) from bX ---
    bf16x8 afh[4][2], afl[4][2];
#pragma unroll
    for (int rt = 0; rt < 4; ++rt)
#pragma unroll
        for (int kt = 0; kt < 2; ++kt) {
            int row = rt * 16 + (lane & 15);
            int s3 = ((kt * 4 + (lane >> 4)) ^ (row & 7)) & 7;
            afh[rt][kt] = *(const bf16x8*)(bX + row * 256 + s3 * 16);
            afl[rt][kt] = *(const bf16x8*)(bX + row * 256 + (8 | s3) * 16);
        }

    const int cl = w * 16 + (lane & 15);   // this wave's code within a chunk

    float m1[16], m2[16];
    int   mi[16];
#pragma unroll
    for (int s = 0; s < 16; ++s) { m1[s] = 3.4e38f; m2[s] = 3.4e38f; mi[s] = 0; }

    // per-thread fragment pointer: chunk stride 16384, pieces at +0/+1024/+2048/+3072
    const char* pc = cbt + (size_t)w * 4096 + (size_t)lane * 16;

    bf16x8 bh0 = *(const bf16x8*)(pc);
    bf16x8 bh1 = *(const bf16x8*)(pc + 1024);
    bf16x8 bl0 = *(const bf16x8*)(pc + 2048);
    bf16x8 bl1 = *(const bf16x8*)(pc + 3072);

#pragma unroll 1
    for (int c = 0; c < 16; ++c) {
        // prefetch next chunk's fragments (c==15 reads the list region: harmless, unused)
        const char* np = pc + 16384;
        bf16x8 nh0 = *(const bf16x8*)(np);
        bf16x8 nh1 = *(const bf16x8*)(np + 1024);
        bf16x8 nl0 = *(const bf16x8*)(np + 2048);
        bf16x8 nl1 = *(const bf16x8*)(np + 3072);

        const int kg = c * 64 + cl;
        const float cbnv = cbn_s[kg];

#pragma unroll
        for (int rt = 0; rt < 4; ++rt) {
            f32x4 z = {0.f, 0.f, 0.f, 0.f};
            z = __builtin_amdgcn_mfma_f32_16x16x32_bf16(afh[rt][0], bh0, z, 0, 0, 0);
            z = __builtin_amdgcn_mfma_f32_16x16x32_bf16(afh[rt][1], bh1, z, 0, 0, 0);
            z = __builtin_amdgcn_mfma_f32_16x16x32_bf16(afl[rt][0], bh0, z, 0, 0, 0);
            z = __builtin_amdgcn_mfma_f32_16x16x32_bf16(afl[rt][1], bh1, z, 0, 0, 0);
            z = __builtin_amdgcn_mfma_f32_16x16x32_bf16(afh[rt][0], bl0, z, 0, 0, 0);
            z = __builtin_amdgcn_mfma_f32_16x16x32_bf16(afh[rt][1], bl1, z, 0, 0, 0);
#pragma unroll
            for (int v = 0; v < 4; ++v) {
                const int s = rt * 4 + v;
                float dd = fmaf(-2.f, z[v], cbnv);
                bool lt = dd < m1[s];
                m2[s] = fminf(m2[s], fmaxf(m1[s], dd));
                m1[s] = fminf(m1[s], dd);
                mi[s] = lt ? kg : mi[s];
            }
        }
        pc = np;
        bh0 = nh0; bh1 = nh1; bl0 = nl0; bl1 = nl1;
    }

    // --- stage A: butterfly reduce over lane&15 ---
#pragma unroll
    for (int m = 1; m <= 8; m <<= 1) {
#pragma unroll
        for (int s = 0; s < 16; ++s) {
            float o1 = __shfl_xor(m1[s], m);
            float o2 = __shfl_xor(m2[s], m);
            int   oi = __shfl_xor(mi[s], m);
            float nm2 = fminf(fminf(m2[s], o2), fmaxf(m1[s], o1));
            bool tk = (o1 < m1[s]) || (o1 == m1[s] && oi < mi[s]);
            m1[s] = fminf(m1[s], o1);
            mi[s] = tk ? oi : mi[s];
            m2[s] = nm2;
        }
    }
    __syncthreads();   // bX (and its af re-reads) done before overlay write
    // --- stage B: one writer per (row, wave) ---
    if ((lane & 15) == 0) {
        const int gq = lane >> 4;
#pragma unroll
        for (int s = 0; s < 16; ++s) {
            const int row = (s >> 2) * 16 + gq * 4 + (s & 3);
            R1[row * 4 + w]  = m1[s];
            R2v[row * 4 + w] = m2[s];
            RIv[row * 4 + w] = mi[s];
        }
    }
    __syncthreads();
    // --- stage C: combine 4 wave-partials; flag decision ---
    {
        const int row = t >> 2, q = t & 3;
        float a1 = R1[row * 4 + q];
        float A2 = R2v[row * 4 + q];
        int   ai = RIv[row * 4 + q];
#pragma unroll
        for (int m = 1; m <= 2; m <<= 1) {
            float o1 = __shfl_xor(a1, m);
            float o2 = __shfl_xor(A2, m);
            int   oi = __shfl_xor(ai, m);
            float nm2 = fminf(fminf(A2, o2), fmaxf(a1, o1));
            bool tk = (o1 < a1) || (o1 == a1 && oi < ai);
            a1 = fminf(a1, o1);
            ai = tk ? oi : ai;
            A2 = nm2;
        }
        if (q == 0) {
            const int r = r0 + row;
            out_idx[r] = (float)ai;
            const float Bv = 1.5e-4f * sqrtf(xx_s[row] * maxcbn) + 2e-3f;
            if (A2 - a1 <= 2.f * Bv) {
                int pos = atomicAdd((int*)(ws + WSO_COUNT), 1);
                list[pos] = (unsigned short)r;
            }
        }
    }
}

// ---- kernel 2: refine v3 — wave per flagged row, d-major coalesced from L2 ----
__global__ void vq_refine(const float* __restrict__ x,
                          const float* __restrict__ cb,
                          const char* __restrict__ ws,
                          const unsigned short* __restrict__ list,
                          float* __restrict__ out_idx) {
    const int N = *(const int*)(ws + WSO_COUNT);
    const float* cbn = (const float*)(ws + WSO_CBN);
    __shared__ float rowx[4][64];
    const int t = threadIdx.x, w = t >> 6, lane = t & 63;

    for (int base = blockIdx.x * 4; base < N; base += (int)gridDim.x * 4) {
        const int ii = base + w;
        const bool valid = ii < N;
        const int r = valid ? (int)list[ii] : (int)list[0];

        __syncthreads();
        const float xv = x[(size_t)r * DIM + lane];
        rowx[w][lane] = xv;
        float p = xv * xv;
#pragma unroll
        for (int m = 1; m < 64; m <<= 1) p += __shfl_xor(p, m);
        const float xx = p;
        __syncthreads();

        float xr[64];
#pragma unroll
        for (int d = 0; d < 64; ++d) xr[d] = rowx[w][d];

        float bd = 3.4e38f;
        int   bk = 0;
        for (int kb = 0; kb < NCODE; kb += 64) {
            float d0 = 0.f, d1 = 0.f, d2 = 0.f, d3 = 0.f;
            const float* cp = cb + kb + lane;
#pragma unroll
            for (int d = 0; d < 64; d += 4) {
                d0 = fmaf(xr[d + 0], cp[(d + 0) * NCODE], d0);
                d1 = fmaf(xr[d + 1], cp[(d + 1) * NCODE], d1);
                d2 = fmaf(xr[d + 2], cp[(d + 2) * NCODE], d2);
                d3 = fmaf(xr[d + 3], cp[(d + 3) * NCODE], d3);
            }
            const float dot = (d0 + d1) + (d2 + d3);
            const float dist = fmaf(-2.f, dot, xx) + cbn[kb + lane];
            const int k = kb + lane;
            if (dist < bd) { bd = dist; bk = k; }
        }
#pragma unroll
        for (int m = 1; m < 64; m <<= 1) {
            float od = __shfl_xor(bd, m);
            int   ok = __shfl_xor(bk, m);
            if (od < bd || (od == bd && ok < bk)) { bd = od; bk = ok; }
        }
        if (lane == 0 && valid) out_idx[r] = (float)bk;
    }
}

// ---- kernel 3: epilogue: gather, straight-through write, loss, histogram ----
__global__ __launch_bounds__(256) void vq_epilogue(const float* __restrict__ x,
                                                   const float* __restrict__ cb,
                                                   const float* __restrict__ idx_f,
                                                   float* __restrict__ out_xq,
                                                   char* __restrict__ ws) {
    const int t = threadIdx.x;
    const int row = blockIdx.x * 64 + (t >> 2), q = t & 3;
    const int k = (int)idx_f[row];
    const float4* xp = (const float4*)(x + (size_t)row * DIM + q * 16);
    float4* op = (float4*)(out_xq + (size_t)row * DIM + q * 16);
    float lsum = 0.f;
#pragma unroll
    for (int j = 0; j < 4; ++j) {
        float4 xv = xp[j];
        const int d0 = q * 16 + 4 * j;
        float q0 = cb[(d0 + 0) * NCODE + k];
        float q1 = cb[(d0 + 1) * NCODE + k];
        float q2 = cb[(d0 + 2) * NCODE + k];
        float q3 = cb[(d0 + 3) * NCODE + k];
        float e0 = q0 - xv.x, e1 = q1 - xv.y, e2 = q2 - xv.z, e3 = q3 - xv.w;
        float4 o;
        o.x = xv.x + e0; o.y = xv.y + e1; o.z = xv.z + e2; o.w = xv.w + e3;
        op[j] = o;
        lsum = fmaf(e0, e0, lsum); lsum = fmaf(e1, e1, lsum);
        lsum = fmaf(e2, e2, lsum); lsum = fmaf(e3, e3, lsum);
    }
    if (q == 0) atomicAdd((float*)(ws + WSO_HIST) + k, 1.0f);
#pragma unroll
    for (int off = 1; off < 64; off <<= 1) lsum += __shfl_xor(lsum, off);
    if ((t & 63) == 0) atomicAdd((float*)(ws + WSO_LOSS), lsum);
}

// ---- kernel 4: EMA + loss finalize ----
__global__ __launch_bounds__(256) void vq_final(const float* __restrict__ cf,
                                                const char* __restrict__ ws,
                                                float* __restrict__ out_loss,
                                                float* __restrict__ out_freq) {
    int k = blockIdx.x * 256 + threadIdx.x;
    out_freq[k] = 0.95f * cf[k] + 0.05f * ((const float*)(ws + WSO_HIST))[k];
    if (k == 0) {
        float m = *(const float*)(ws + WSO_LOSS) / 4194304.0f;
        out_loss[0] = m + m;
    }
}

extern "C" void kernel_launch(void* const* d_in, const int* in_sizes, int n_in,
                              void* d_out, int out_size, void* d_ws, size_t ws_size,
                              hipStream_t stream) {
    const float* x  = (const float*)d_in[0];   // [16,4096,64]
    const float* cb = (const float*)d_in[1];   // [64,1024]
    const float* cf = (const float*)d_in[2];   // [1024]

    float* out      = (float*)d_out;
    float* out_xq   = out;                     // 4,194,304 floats
    float* out_idx  = out + 4194304;           // 65,536
    float* out_loss = out + 4194304 + 65536;   // 1
    float* out_freq = out_loss + 1;            // 1024

    char* ws = (char*)d_ws;                    // 8,256 bytes used

    // big scratch inside out_xq (free until epilogue overwrites it)
    char*           cbt  = (char*)d_out;                               // 262,144 B
    unsigned short* list = (unsigned short*)((char*)d_out + 262144);   // 131,072 B

    vq_prep    <<<4,    256, 0, stream>>>(cb, ws, cbt);
    vq_mfma    <<<1024, 256, 0, stream>>>(x, cbt, ws, list, out_idx);
    vq_refine  <<<2048, 256, 0, stream>>>(x, cb, ws, list, out_idx);
    vq_epilogue<<<1024, 256, 0, stream>>>(x, cb, out_idx, out_xq, ws);
    vq_final   <<<4,    256, 0, stream>>>(cf, ws, out_loss, out_freq);
}